// Round 8
// baseline (254.107 us; speedup 1.0000x reference)
//
#include <hip/hip_runtime.h>
#include <hip/hip_bf16.h>

// VectorQuantiser: x [32,64,64,64] f32, embeddings [64,1024] f32.
// argmin_k ||z - e_k||^2 over K=1024 for N=131072 rows of D=64; out = codewords.
//
//  k0 vq_prep:   ET[k][d] f32; ckseq[k] = sequential f32 sum e^2 (numpy order);
//                EB = bf16 hi/lo fragments of (-2e) in lane-linear segment order
//                (16 rounds x 16 segs x 64 lanes x 16 B) for global_load_lds.
//  k1 vq_mfma:   score = ck - 2*dot via two independent depth-3 MFMA chains
//                (chainA: d0-31 xh*eh, xl*eh, xh*el; chainB: d32-63, C-in=ck).
//                64-col rounds, LDS double buffer via global_load_lds w=16.
//                Branchless top-2; gap < MARGIN -> refine list.
//  k2 vq_refine2: wave per flagged row: exact numpy-f32 chain over all 1024 k
//                (coalesced E[d][k] loads), packed-key argmin (dist,k) lex-min,
//                direct gather rewrite. Semantics validated R2-R7.

#define NROWS (32 * 64 * 64)   // 131072
#define DIM   64
#define KCB   1024
#define MARGIN 1.5e-4f

// ws layout (bytes):
#define ET_OFF    0           // float[1024*64] = 262144
#define CK_OFF    262144      // float[1088] pad -> 4352
#define EB_OFF    266496      // 16 rounds * 16384 B = 262144
#define CNT_OFF   528640      // int (+pad)
#define LIST_OFF  528896      // int[cap]
#define LIST_CAP  8192

typedef float  f32x4 __attribute__((ext_vector_type(4)));
typedef short  s16x8 __attribute__((ext_vector_type(8)));

#define GLDS16(g, l) __builtin_amdgcn_global_load_lds( \
    (const __attribute__((address_space(1))) unsigned int*)(g), \
    (__attribute__((address_space(3))) unsigned int*)(l), 16, 0, 0)

static __device__ inline short bfb(float f) {   // f32 -> bf16 bits, RNE
    union { float f; unsigned u; } c{f};
    unsigned r = c.u + 0x7fffu + ((c.u >> 16) & 1u);
    return (short)(r >> 16);
}
static __device__ inline float bf2f(short b) {  // bf16 bits -> f32
    union { unsigned u; float f; } c{(unsigned)(unsigned short)b << 16};
    return c.f;
}

__global__ void vq_prep(const float* __restrict__ E,
                        float* __restrict__ ET,
                        float* __restrict__ ckseq,
                        char* __restrict__ EB) {
    #pragma clang fp contract(off)
    int n = blockIdx.x * blockDim.x + threadIdx.x;  // codebook col 0..1023
    if (n >= KCB) return;
    float col[DIM];
    float c = 0.f;
    #pragma unroll
    for (int d = 0; d < DIM; ++d) {
        float v = E[d * KCB + n];      // coalesced along n
        col[d] = v;
        ET[n * DIM + d] = v;
        float q = v * v;
        c = c + q;                     // sequential (numpy axis-0 reduce)
    }
    ckseq[n] = c;
    // EB segment layout: round r = n>>6 (64 cols), half-tile ht = (n>>4)&3
    // (16 cols), col-in-tile l15 = n&15. Part p: 0=hi d0-31, 1=hi d32-63,
    // 2=lo d0-31, 3=lo d32-63. Lane l = g*16+l15 holds d = (p&1)*32+g*8+j.
    // 16 B per lane at EB + r*16384 + (ht*4+p)*1024 + l*16.
    int r = n >> 6, ht = (n >> 4) & 3, l15 = n & 15;
    char* base = EB + r * 16384 + ht * 4096;
    #pragma unroll
    for (int p = 0; p < 4; ++p) {
        int dblk = p & 1, islo = p >> 1;
        #pragma unroll
        for (int g = 0; g < 4; ++g) {
            s16x8 w;
            #pragma unroll
            for (int j = 0; j < 8; ++j) {
                float m = -2.f * col[dblk * 32 + g * 8 + j];  // exact scale
                short h = bfb(m);
                w[j] = islo ? bfb(m - bf2f(h)) : h;
            }
            *(s16x8*)(base + p * 1024 + (g * 16 + l15) * 16) = w;
        }
    }
}

__global__ __launch_bounds__(256, 4)
void vq_mfma(const float* __restrict__ x, const float* __restrict__ ck,
             const char* __restrict__ EB, const float* __restrict__ ET,
             float* __restrict__ out, int* __restrict__ count,
             int* __restrict__ list, int list_cap) {
    __shared__ alignas(16) char bufs[2][16384];   // B round double buffer
    __shared__ float ckls[KCB];
    __shared__ int idxbuf[128];

    const int tid  = threadIdx.x;
    const int lane = tid & 63;
    const int wv   = tid >> 6;            // wave 0..3
    const int l15  = lane & 15;
    const int g    = lane >> 4;           // 0..3
    const int rowbase = blockIdx.x * 128; // 128 rows per block, 32 per wave

    // ---- A fragments hi/lo: 2 rowtiles x 2 dblocks (32 VGPR persistent) ----
    s16x8 aH[2][2], aL[2][2];
    #pragma unroll
    for (int rt = 0; rt < 2; ++rt) {
        int row = rowbase + wv * 32 + rt * 16 + l15;
        const float* xp = x + (size_t)row * DIM + g * 8;
        #pragma unroll
        for (int s = 0; s < 2; ++s) {
            float val[8];
            float4 u = *(const float4*)(xp + s * 32);
            float4 v = *(const float4*)(xp + s * 32 + 4);
            val[0] = u.x; val[1] = u.y; val[2] = u.z; val[3] = u.w;
            val[4] = v.x; val[5] = v.y; val[6] = v.z; val[7] = v.w;
            s16x8 h, l;
            #pragma unroll
            for (int j = 0; j < 8; ++j) {
                short hb = bfb(val[j]);
                h[j] = hb;
                l[j] = bfb(val[j] - bf2f(hb));
            }
            aH[rt][s] = h;
            aL[rt][s] = l;
        }
    }

    // ---- prologue staging: ck (4 KB) + round 0 (16 KB) via global_load_lds --
    GLDS16(ck + wv * 256 + lane * 4, &ckls[wv * 256]);
    #pragma unroll
    for (int i = 0; i < 4; ++i) {
        int seg = wv * 4 + i;
        GLDS16(EB + seg * 1024 + lane * 16, &bufs[0][seg * 1024]);
    }
    __syncthreads();

    // ---- top-2 state: slot = rt*4 + r -> row rt*16 + g*4 + r ----
    float tb1[8], tb2[8];
    int   tix[8];
    #pragma unroll
    for (int sl = 0; sl < 8; ++sl) { tb1[sl] = 1e30f; tb2[sl] = 1e30f; tix[sl] = 0; }

    const f32x4 kzero = {0.f, 0.f, 0.f, 0.f};

    #pragma unroll 2
    for (int r = 0; r < 16; ++r) {
        const int cur = r & 1;
        if (r < 15) {                       // prefetch next round (T14)
            const char* src = EB + (r + 1) * 16384;
            #pragma unroll
            for (int i = 0; i < 4; ++i) {
                int seg = wv * 4 + i;
                GLDS16(src + seg * 1024 + lane * 16, &bufs[cur ^ 1][seg * 1024]);
            }
        }
        #pragma unroll
        for (int ht = 0; ht < 4; ++ht) {
            const char* sb = &bufs[cur][ht * 4096];
            s16x8 ch0 = *(const s16x8*)(sb + lane * 16);
            s16x8 ch1 = *(const s16x8*)(sb + 1024 + lane * 16);
            s16x8 cl0 = *(const s16x8*)(sb + 2048 + lane * 16);
            s16x8 cl1 = *(const s16x8*)(sb + 3072 + lane * 16);
            float cck = ckls[r * 64 + ht * 16 + l15];
            f32x4 cin = {cck, cck, cck, cck};
            int kc = r * 64 + ht * 16 + l15;
            #pragma unroll
            for (int rt = 0; rt < 2; ++rt) {
                // two independent depth-3 chains -> latency hidden
                f32x4 accA, accB;
                accA = __builtin_amdgcn_mfma_f32_16x16x32_bf16(aH[rt][0], ch0, kzero, 0, 0, 0);
                accB = __builtin_amdgcn_mfma_f32_16x16x32_bf16(aH[rt][1], ch1, cin,   0, 0, 0);
                accA = __builtin_amdgcn_mfma_f32_16x16x32_bf16(aL[rt][0], ch0, accA,  0, 0, 0);
                accB = __builtin_amdgcn_mfma_f32_16x16x32_bf16(aL[rt][1], ch1, accB,  0, 0, 0);
                accA = __builtin_amdgcn_mfma_f32_16x16x32_bf16(aH[rt][0], cl0, accA,  0, 0, 0);
                accB = __builtin_amdgcn_mfma_f32_16x16x32_bf16(aH[rt][1], cl1, accB,  0, 0, 0);
                #pragma unroll
                for (int rr = 0; rr < 4; ++rr) {
                    float s = accA[rr] + accB[rr];   // = ck - 2*dot
                    int sl = rt * 4 + rr;
                    bool cond = s < tb1[sl];
                    tb2[sl] = __builtin_amdgcn_fmed3f(s, tb1[sl], tb2[sl]);
                    tb1[sl] = fminf(tb1[sl], s);
                    tix[sl] = cond ? kc : tix[sl];
                }
            }
        }
        __syncthreads();   // drains vmcnt -> next buffer ready, cur consumed
    }

    // ---- merge top-2 across the 16 lanes of each g-group ----
    #pragma unroll
    for (int m = 1; m <= 8; m <<= 1) {
        #pragma unroll
        for (int sl = 0; sl < 8; ++sl) {
            float ob1 = __shfl_xor(tb1[sl], m);
            float ob2 = __shfl_xor(tb2[sl], m);
            int   oid = __shfl_xor(tix[sl], m);
            if (ob1 < tb1[sl] || (ob1 == tb1[sl] && oid < tix[sl])) {
                tb2[sl] = fminf(tb1[sl], ob2);
                tb1[sl] = ob1;
                tix[sl] = oid;
            } else {
                tb2[sl] = fminf(tb2[sl], ob1);
            }
        }
    }

    if (l15 == 0) {
        #pragma unroll
        for (int sl = 0; sl < 8; ++sl) {
            int rloc = wv * 32 + (sl >> 2) * 16 + g * 4 + (sl & 3);
            idxbuf[rloc] = tix[sl];
            if (tb2[sl] - tb1[sl] < MARGIN) {
                int slot = atomicAdd(count, 1);
                if (slot < list_cap) list[slot] = rowbase + rloc;
            }
        }
    }
    __syncthreads();

    // ---- fused gather: out[rowbase + r][:] = ET[idx[r]][:] ----
    const float4* ET4 = (const float4*)ET;
    float4* out4 = (float4*)(out + (size_t)rowbase * DIM);
    #pragma unroll
    for (int p = 0; p < 8; ++p) {
        int f = p * 256 + tid;           // 0..2047
        int r = f >> 4, dq = f & 15;
        out4[f] = ET4[idxbuf[r] * 16 + dq];
    }
}

// Exact numpy-f32-chain argmin for flagged rows (semantics validated R2-R7).
// One wave per row; lane handles 16 k's (k = c*64 + lane, coalesced E[d][k]
// loads, 2 chains interleaved). Packed-key (ordbits(dist)<<32)|k lex-min
// gives exact first-index tie-break. Gathers + rewrites the row directly.
__global__ __launch_bounds__(256)
void vq_refine2(const float* __restrict__ x, const float* __restrict__ E,
                const float* __restrict__ ckseq, const float* __restrict__ ET,
                float* __restrict__ out,
                const int* __restrict__ count, const int* __restrict__ list,
                int list_cap) {
    #pragma clang fp contract(off)
    int n = *count;
    if (n > list_cap) n = list_cap;
    int gw = (blockIdx.x * blockDim.x + threadIdx.x) >> 6;
    int lane = threadIdx.x & 63;
    int nw = (gridDim.x * blockDim.x) >> 6;
    for (int slot = gw; slot < n; slot += nw) {
        int row = list[slot];
        const f32x4* z4 = (const f32x4*)(x + (size_t)row * DIM);

        // ||z||^2: numpy pairwise_sum n=64 (8-acc unrolled), validated order
        float r8[8];
        {
            f32x4 a = z4[0], b = z4[1];
            r8[0] = a.x * a.x; r8[1] = a.y * a.y; r8[2] = a.z * a.z; r8[3] = a.w * a.w;
            r8[4] = b.x * b.x; r8[5] = b.y * b.y; r8[6] = b.z * b.z; r8[7] = b.w * b.w;
        }
        #pragma unroll
        for (int gi = 1; gi < 8; ++gi) {
            f32x4 a = z4[gi * 2], b = z4[gi * 2 + 1];
            r8[0] = r8[0] + a.x * a.x; r8[1] = r8[1] + a.y * a.y;
            r8[2] = r8[2] + a.z * a.z; r8[3] = r8[3] + a.w * a.w;
            r8[4] = r8[4] + b.x * b.x; r8[5] = r8[5] + b.y * b.y;
            r8[6] = r8[6] + b.z * b.z; r8[7] = r8[7] + b.w * b.w;
        }
        float A = ((r8[0] + r8[1]) + (r8[2] + r8[3]))
                + ((r8[4] + r8[5]) + (r8[6] + r8[7]));

        unsigned long long key = ~0ull;
        for (int c = 0; c < 16; c += 2) {     // 2 chains interleaved
            int k0 = c * 64 + lane, k1 = k0 + 64;
            float s0 = 0.f, s1 = 0.f;
            #pragma unroll
            for (int q = 0; q < 16; ++q) {    // sequential fmaf over d (BLAS emu)
                f32x4 zv = z4[q];
                s0 = fmaf(zv.x, E[(4 * q + 0) * KCB + k0], s0);
                s1 = fmaf(zv.x, E[(4 * q + 0) * KCB + k1], s1);
                s0 = fmaf(zv.y, E[(4 * q + 1) * KCB + k0], s0);
                s1 = fmaf(zv.y, E[(4 * q + 1) * KCB + k1], s1);
                s0 = fmaf(zv.z, E[(4 * q + 2) * KCB + k0], s0);
                s1 = fmaf(zv.z, E[(4 * q + 2) * KCB + k1], s1);
                s0 = fmaf(zv.w, E[(4 * q + 3) * KCB + k0], s0);
                s1 = fmaf(zv.w, E[(4 * q + 3) * KCB + k1], s1);
            }
            float d0 = (A + ckseq[k0]) - 2.0f * s0;
            float d1 = (A + ckseq[k1]) - 2.0f * s1;
            unsigned u0 = __float_as_uint(d0);
            unsigned o0 = u0 ^ ((u0 & 0x80000000u) ? 0xFFFFFFFFu : 0x80000000u);
            unsigned u1 = __float_as_uint(d1);
            unsigned o1 = u1 ^ ((u1 & 0x80000000u) ? 0xFFFFFFFFu : 0x80000000u);
            unsigned long long key0 = ((unsigned long long)o0 << 32) | (unsigned)k0;
            unsigned long long key1 = ((unsigned long long)o1 << 32) | (unsigned)k1;
            key = key0 < key ? key0 : key;
            key = key1 < key ? key1 : key;
        }
        #pragma unroll
        for (int off = 32; off; off >>= 1) {
            unsigned long long ok = __shfl_xor(key, off);
            key = ok < key ? ok : key;
        }
        unsigned bk = (unsigned)(key & 0xFFFFFFFFu);
        out[(size_t)row * DIM + lane] = ET[(size_t)bk * DIM + lane];
    }
}

extern "C" void kernel_launch(void* const* d_in, const int* in_sizes, int n_in,
                              void* d_out, int out_size, void* d_ws, size_t ws_size,
                              hipStream_t stream) {
    const float* x = (const float*)d_in[0];
    const float* E = (const float*)d_in[1];
    float* out = (float*)d_out;

    char* ws = (char*)d_ws;
    float* ET  = (float*)(ws + ET_OFF);
    float* ck  = (float*)(ws + CK_OFF);
    char*  EB  = ws + EB_OFF;
    int*   cnt = (int*)(ws + CNT_OFF);
    int*   lst = (int*)(ws + LIST_OFF);
    long long avail = (long long)ws_size - LIST_OFF;
    int list_cap = avail > 0 ? (int)(avail / 4) : 0;
    if (list_cap > LIST_CAP) list_cap = LIST_CAP;

    hipMemsetAsync(cnt, 0, sizeof(int), stream);
    vq_prep<<<4, 256, 0, stream>>>(E, ET, ck, EB);
    vq_mfma<<<NROWS / 128, 256, 0, stream>>>(x, ck, EB, ET, out, cnt, lst, list_cap);
    vq_refine2<<<512, 256, 0, stream>>>(x, E, ck, ET, out, cnt, lst, list_cap);
}

// Round 9
// 108.023 us; speedup vs baseline: 2.3523x; 2.3523x over previous
//
#include <hip/hip_runtime.h>
#include <hip/hip_bf16.h>

// VectorQuantiser: x [32,64,64,64] f32, embeddings [64,1024] f32.
// argmin_k ||z - e_k||^2 over K=1024 for N=131072 rows of D=64; out = codewords.
//
//  k0 vq_prep:   ET[k][d] f32; ckseq[k] = sequential f32 sum e^2 (numpy order);
//                EB = bf16 hi/lo fragments of (-2e), lane-linear, 32 rounds
//                of 8192 B (2 tiles x 4 parts x 1024 B) for global_load_lds.
//  k1 vq_mfma:   score = ck - 2*dot via two independent depth-3 MFMA chains.
//                2-tile rounds, 8 KB LDS double buffer via global_load_lds.
//                amdgpu_waves_per_eu(4,4) pins the VGPR budget at 128 (the
//                R7/R8 spill catastrophe was the allocator chasing 8 waves).
//                Branchless top-2; gap < MARGIN -> refine list.
//  k2 vq_refine2: wave per flagged row: exact numpy-f32 chain over all 1024 k
//                (coalesced E[d][k] loads), packed-key argmin, direct rewrite.
//                Semantics validated R2-R8.

#define NROWS (32 * 64 * 64)   // 131072
#define DIM   64
#define KCB   1024
#define MARGIN 1.5e-4f

// ws layout (bytes):
#define ET_OFF    0           // float[1024*64] = 262144
#define CK_OFF    262144      // float[1088] pad -> 4352
#define EB_OFF    266496      // 32 rounds * 8192 B = 262144
#define CNT_OFF   528640      // int (+pad)
#define LIST_OFF  528896      // int[cap]
#define LIST_CAP  8192

typedef float  f32x4 __attribute__((ext_vector_type(4)));
typedef short  s16x8 __attribute__((ext_vector_type(8)));

#define GLDS16(g, l) __builtin_amdgcn_global_load_lds( \
    (const __attribute__((address_space(1))) unsigned int*)(g), \
    (__attribute__((address_space(3))) unsigned int*)(l), 16, 0, 0)

static __device__ inline short bfb(float f) {   // f32 -> bf16 bits, RNE
    union { float f; unsigned u; } c{f};
    unsigned r = c.u + 0x7fffu + ((c.u >> 16) & 1u);
    return (short)(r >> 16);
}
static __device__ inline float bf2f(short b) {  // bf16 bits -> f32
    union { unsigned u; float f; } c{(unsigned)(unsigned short)b << 16};
    return c.f;
}

__global__ void vq_prep(const float* __restrict__ E,
                        float* __restrict__ ET,
                        float* __restrict__ ckseq,
                        char* __restrict__ EB) {
    #pragma clang fp contract(off)
    int n = blockIdx.x * blockDim.x + threadIdx.x;  // codebook col 0..1023
    if (n >= KCB) return;
    float col[DIM];
    float c = 0.f;
    #pragma unroll
    for (int d = 0; d < DIM; ++d) {
        float v = E[d * KCB + n];      // coalesced along n
        col[d] = v;
        ET[n * DIM + d] = v;
        float q = v * v;
        c = c + q;                     // sequential (numpy axis-0 reduce)
    }
    ckseq[n] = c;
    // EB layout: round r = n>>5 (32 cols), tile ht = (n>>4)&1 (16 cols),
    // col-in-tile l15 = n&15. Part p: 0=hi d0-31, 1=hi d32-63, 2=lo d0-31,
    // 3=lo d32-63. Lane l = g*16+l15 holds d = (p&1)*32 + g*8 + j, j=0..7.
    // 16 B per lane at EB + r*8192 + ht*4096 + p*1024 + l*16.
    int r = n >> 5, ht = (n >> 4) & 1, l15 = n & 15;
    char* base = EB + r * 8192 + ht * 4096;
    #pragma unroll
    for (int p = 0; p < 4; ++p) {
        int dblk = p & 1, islo = p >> 1;
        #pragma unroll
        for (int g = 0; g < 4; ++g) {
            s16x8 w;
            #pragma unroll
            for (int j = 0; j < 8; ++j) {
                float m = -2.f * col[dblk * 32 + g * 8 + j];  // exact scale
                short h = bfb(m);
                w[j] = islo ? bfb(m - bf2f(h)) : h;
            }
            *(s16x8*)(base + p * 1024 + (g * 16 + l15) * 16) = w;
        }
    }
}

__global__ __launch_bounds__(256)
__attribute__((amdgpu_waves_per_eu(4, 4)))
void vq_mfma(const float* __restrict__ x, const float* __restrict__ ck,
             const char* __restrict__ EB, const float* __restrict__ ET,
             float* __restrict__ out, int* __restrict__ count,
             int* __restrict__ list, int list_cap) {
    __shared__ alignas(16) char bufs[2][8192];   // 2-tile round double buffer
    __shared__ float ckls[KCB];
    __shared__ int idxbuf[128];

    const int tid  = threadIdx.x;
    const int lane = tid & 63;
    const int wv   = tid >> 6;            // wave 0..3
    const int l15  = lane & 15;
    const int g    = lane >> 4;           // 0..3
    const int rowbase = blockIdx.x * 128; // 128 rows per block, 32 per wave

    // ---- A fragments hi/lo: 2 rowtiles x 2 dblocks (32 VGPR persistent) ----
    s16x8 aH[2][2], aL[2][2];
    #pragma unroll
    for (int rt = 0; rt < 2; ++rt) {
        int row = rowbase + wv * 32 + rt * 16 + l15;
        const float* xp = x + (size_t)row * DIM + g * 8;
        #pragma unroll
        for (int s = 0; s < 2; ++s) {
            float val[8];
            float4 u = *(const float4*)(xp + s * 32);
            float4 v = *(const float4*)(xp + s * 32 + 4);
            val[0] = u.x; val[1] = u.y; val[2] = u.z; val[3] = u.w;
            val[4] = v.x; val[5] = v.y; val[6] = v.z; val[7] = v.w;
            s16x8 h, l;
            #pragma unroll
            for (int j = 0; j < 8; ++j) {
                short hb = bfb(val[j]);
                h[j] = hb;
                l[j] = bfb(val[j] - bf2f(hb));
            }
            aH[rt][s] = h;
            aL[rt][s] = l;
        }
    }

    // ---- prologue staging: ck (4 KB) + round 0 (8 KB) via global_load_lds --
    GLDS16(ck + wv * 256 + lane * 4, &ckls[wv * 256]);
    #pragma unroll
    for (int i = 0; i < 2; ++i) {
        int seg = wv * 2 + i;
        GLDS16(EB + seg * 1024 + lane * 16, &bufs[0][seg * 1024]);
    }
    __syncthreads();

    // ---- top-2 state: slot = rt*4 + r -> row rt*16 + g*4 + r ----
    float tb1[8], tb2[8];
    int   tix[8];
    #pragma unroll
    for (int sl = 0; sl < 8; ++sl) { tb1[sl] = 1e30f; tb2[sl] = 1e30f; tix[sl] = 0; }

    const f32x4 kzero = {0.f, 0.f, 0.f, 0.f};

    #pragma unroll 1
    for (int r = 0; r < 32; ++r) {
        const int cur = r & 1;
        if (r < 31) {                       // prefetch next round (T14)
            const char* src = EB + (r + 1) * 8192;
            #pragma unroll
            for (int i = 0; i < 2; ++i) {
                int seg = wv * 2 + i;
                GLDS16(src + seg * 1024 + lane * 16, &bufs[cur ^ 1][seg * 1024]);
            }
        }
        #pragma unroll
        for (int ht = 0; ht < 2; ++ht) {
            const char* sb = &bufs[cur][ht * 4096];
            s16x8 ch0 = *(const s16x8*)(sb + lane * 16);
            s16x8 ch1 = *(const s16x8*)(sb + 1024 + lane * 16);
            s16x8 cl0 = *(const s16x8*)(sb + 2048 + lane * 16);
            s16x8 cl1 = *(const s16x8*)(sb + 3072 + lane * 16);
            float cck = ckls[r * 32 + ht * 16 + l15];
            f32x4 cin = {cck, cck, cck, cck};
            int kc = r * 32 + ht * 16 + l15;
            #pragma unroll
            for (int rt = 0; rt < 2; ++rt) {
                // two independent depth-3 chains -> MFMA latency hidden
                f32x4 accA, accB;
                accA = __builtin_amdgcn_mfma_f32_16x16x32_bf16(aH[rt][0], ch0, kzero, 0, 0, 0);
                accB = __builtin_amdgcn_mfma_f32_16x16x32_bf16(aH[rt][1], ch1, cin,   0, 0, 0);
                accA = __builtin_amdgcn_mfma_f32_16x16x32_bf16(aL[rt][0], ch0, accA,  0, 0, 0);
                accB = __builtin_amdgcn_mfma_f32_16x16x32_bf16(aL[rt][1], ch1, accB,  0, 0, 0);
                accA = __builtin_amdgcn_mfma_f32_16x16x32_bf16(aH[rt][0], cl0, accA,  0, 0, 0);
                accB = __builtin_amdgcn_mfma_f32_16x16x32_bf16(aH[rt][1], cl1, accB,  0, 0, 0);
                #pragma unroll
                for (int rr = 0; rr < 4; ++rr) {
                    float s = accA[rr] + accB[rr];   // = ck - 2*dot
                    int sl = rt * 4 + rr;
                    bool cond = s < tb1[sl];
                    tb2[sl] = __builtin_amdgcn_fmed3f(s, tb1[sl], tb2[sl]);
                    tb1[sl] = fminf(tb1[sl], s);
                    tix[sl] = cond ? kc : tix[sl];
                }
            }
        }
        __syncthreads();   // drains vmcnt -> next buffer ready, cur consumed
    }

    // ---- merge top-2 across the 16 lanes of each g-group ----
    #pragma unroll
    for (int m = 1; m <= 8; m <<= 1) {
        #pragma unroll
        for (int sl = 0; sl < 8; ++sl) {
            float ob1 = __shfl_xor(tb1[sl], m);
            float ob2 = __shfl_xor(tb2[sl], m);
            int   oid = __shfl_xor(tix[sl], m);
            if (ob1 < tb1[sl] || (ob1 == tb1[sl] && oid < tix[sl])) {
                tb2[sl] = fminf(tb1[sl], ob2);
                tb1[sl] = ob1;
                tix[sl] = oid;
            } else {
                tb2[sl] = fminf(tb2[sl], ob1);
            }
        }
    }

    if (l15 == 0) {
        #pragma unroll
        for (int sl = 0; sl < 8; ++sl) {
            int rloc = wv * 32 + (sl >> 2) * 16 + g * 4 + (sl & 3);
            idxbuf[rloc] = tix[sl];
            if (tb2[sl] - tb1[sl] < MARGIN) {
                int slot = atomicAdd(count, 1);
                if (slot < list_cap) list[slot] = rowbase + rloc;
            }
        }
    }
    __syncthreads();

    // ---- fused gather: out[rowbase + r][:] = ET[idx[r]][:] ----
    const float4* ET4 = (const float4*)ET;
    float4* out4 = (float4*)(out + (size_t)rowbase * DIM);
    #pragma unroll
    for (int p = 0; p < 8; ++p) {
        int f = p * 256 + tid;           // 0..2047
        int r = f >> 4, dq = f & 15;
        out4[f] = ET4[idxbuf[r] * 16 + dq];
    }
}

// Exact numpy-f32-chain argmin for flagged rows (semantics validated R2-R8).
// One wave per row; lane handles 16 k's (k = c*64 + lane, coalesced E[d][k]
// loads, 2 chains interleaved). Packed-key (ordbits(dist)<<32)|k lex-min
// gives exact first-index tie-break. Gathers + rewrites the row directly.
__global__ __launch_bounds__(256)
void vq_refine2(const float* __restrict__ x, const float* __restrict__ E,
                const float* __restrict__ ckseq, const float* __restrict__ ET,
                float* __restrict__ out,
                const int* __restrict__ count, const int* __restrict__ list,
                int list_cap) {
    #pragma clang fp contract(off)
    int n = *count;
    if (n > list_cap) n = list_cap;
    int gw = (blockIdx.x * blockDim.x + threadIdx.x) >> 6;
    int lane = threadIdx.x & 63;
    int nw = (gridDim.x * blockDim.x) >> 6;
    for (int slot = gw; slot < n; slot += nw) {
        int row = list[slot];
        const f32x4* z4 = (const f32x4*)(x + (size_t)row * DIM);

        // ||z||^2: numpy pairwise_sum n=64 (8-acc unrolled), validated order
        float r8[8];
        {
            f32x4 a = z4[0], b = z4[1];
            r8[0] = a.x * a.x; r8[1] = a.y * a.y; r8[2] = a.z * a.z; r8[3] = a.w * a.w;
            r8[4] = b.x * b.x; r8[5] = b.y * b.y; r8[6] = b.z * b.z; r8[7] = b.w * b.w;
        }
        #pragma unroll
        for (int gi = 1; gi < 8; ++gi) {
            f32x4 a = z4[gi * 2], b = z4[gi * 2 + 1];
            r8[0] = r8[0] + a.x * a.x; r8[1] = r8[1] + a.y * a.y;
            r8[2] = r8[2] + a.z * a.z; r8[3] = r8[3] + a.w * a.w;
            r8[4] = r8[4] + b.x * b.x; r8[5] = r8[5] + b.y * b.y;
            r8[6] = r8[6] + b.z * b.z; r8[7] = r8[7] + b.w * b.w;
        }
        float A = ((r8[0] + r8[1]) + (r8[2] + r8[3]))
                + ((r8[4] + r8[5]) + (r8[6] + r8[7]));

        unsigned long long key = ~0ull;
        for (int c = 0; c < 16; c += 2) {     // 2 chains interleaved
            int k0 = c * 64 + lane, k1 = k0 + 64;
            float s0 = 0.f, s1 = 0.f;
            #pragma unroll
            for (int q = 0; q < 16; ++q) {    // sequential fmaf over d (BLAS emu)
                f32x4 zv = z4[q];
                s0 = fmaf(zv.x, E[(4 * q + 0) * KCB + k0], s0);
                s1 = fmaf(zv.x, E[(4 * q + 0) * KCB + k1], s1);
                s0 = fmaf(zv.y, E[(4 * q + 1) * KCB + k0], s0);
                s1 = fmaf(zv.y, E[(4 * q + 1) * KCB + k1], s1);
                s0 = fmaf(zv.z, E[(4 * q + 2) * KCB + k0], s0);
                s1 = fmaf(zv.z, E[(4 * q + 2) * KCB + k1], s1);
                s0 = fmaf(zv.w, E[(4 * q + 3) * KCB + k0], s0);
                s1 = fmaf(zv.w, E[(4 * q + 3) * KCB + k1], s1);
            }
            float d0 = (A + ckseq[k0]) - 2.0f * s0;
            float d1 = (A + ckseq[k1]) - 2.0f * s1;
            unsigned u0 = __float_as_uint(d0);
            unsigned o0 = u0 ^ ((u0 & 0x80000000u) ? 0xFFFFFFFFu : 0x80000000u);
            unsigned u1 = __float_as_uint(d1);
            unsigned o1 = u1 ^ ((u1 & 0x80000000u) ? 0xFFFFFFFFu : 0x80000000u);
            unsigned long long key0 = ((unsigned long long)o0 << 32) | (unsigned)k0;
            unsigned long long key1 = ((unsigned long long)o1 << 32) | (unsigned)k1;
            key = key0 < key ? key0 : key;
            key = key1 < key ? key1 : key;
        }
        #pragma unroll
        for (int off = 32; off; off >>= 1) {
            unsigned long long ok = __shfl_xor(key, off);
            key = ok < key ? ok : key;
        }
        unsigned bk = (unsigned)(key & 0xFFFFFFFFu);
        out[(size_t)row * DIM + lane] = ET[(size_t)bk * DIM + lane];
    }
}

extern "C" void kernel_launch(void* const* d_in, const int* in_sizes, int n_in,
                              void* d_out, int out_size, void* d_ws, size_t ws_size,
                              hipStream_t stream) {
    const float* x = (const float*)d_in[0];
    const float* E = (const float*)d_in[1];
    float* out = (float*)d_out;

    char* ws = (char*)d_ws;
    float* ET  = (float*)(ws + ET_OFF);
    float* ck  = (float*)(ws + CK_OFF);
    char*  EB  = ws + EB_OFF;
    int*   cnt = (int*)(ws + CNT_OFF);
    int*   lst = (int*)(ws + LIST_OFF);
    long long avail = (long long)ws_size - LIST_OFF;
    int list_cap = avail > 0 ? (int)(avail / 4) : 0;
    if (list_cap > LIST_CAP) list_cap = LIST_CAP;

    hipMemsetAsync(cnt, 0, sizeof(int), stream);
    vq_prep<<<4, 256, 0, stream>>>(E, ET, ck, EB);
    vq_mfma<<<NROWS / 128, 256, 0, stream>>>(x, ck, EB, ET, out, cnt, lst, list_cap);
    vq_refine2<<<512, 256, 0, stream>>>(x, E, ck, ET, out, cnt, lst, list_cap);
}

// Round 10
// 107.866 us; speedup vs baseline: 2.3558x; 1.0015x over previous
//
#include <hip/hip_runtime.h>
#include <hip/hip_bf16.h>

// VectorQuantiser: x [32,64,64,64] f32, embeddings [64,1024] f32.
// argmin_k ||z - e_k||^2 over K=1024 for N=131072 rows of D=64; out = codewords.
//
//  k0 vq_prep:   ET[k][d] f32; ckseq[k] = sequential f32 sum e^2 (numpy order);
//                EB = bf16 hi/lo fragments of (-2e), lane-linear, 64 tiles
//                of 4096 B (+1 pad tile) for direct per-wave register loads.
//  k1 vq_mfma:   BARRIER-FREE K-loop (R9 post-mortem: 75us was sync/latency-
//                bound, all pipes <30%). Each wave privately streams B tiles
//                from L2 with depth-1 register prefetch; score = ck - 2*dot
//                via one 6-deep C-chained MFMA chain per row-tile (C-fwd is
//                full rate). Branchless top-2; gap < MARGIN -> refine list.
//  k2 vq_refine2: wave per flagged row: exact numpy-f32 chain over all 1024 k
//                (coalesced E[d][k] loads), packed-key argmin, direct rewrite.
//                Semantics validated R2-R9.

#define NROWS (32 * 64 * 64)   // 131072
#define DIM   64
#define KCB   1024
#define MARGIN 1.5e-4f

// ws layout (bytes):
#define ET_OFF    0           // float[1024*64] = 262144
#define CK_OFF    262144      // float[1088] pad -> 4352
#define EB_OFF    266496      // 65 tiles * 4096 B = 266240 (64 + 1 prefetch pad)
#define CNT_OFF   532736      // int (+pad)
#define LIST_OFF  532992      // int[cap]
#define LIST_CAP  8192

typedef float  f32x4 __attribute__((ext_vector_type(4)));
typedef short  s16x8 __attribute__((ext_vector_type(8)));

#define GLDS16(g, l) __builtin_amdgcn_global_load_lds( \
    (const __attribute__((address_space(1))) unsigned int*)(g), \
    (__attribute__((address_space(3))) unsigned int*)(l), 16, 0, 0)

static __device__ inline short bfb(float f) {   // f32 -> bf16 bits, RNE
    union { float f; unsigned u; } c{f};
    unsigned r = c.u + 0x7fffu + ((c.u >> 16) & 1u);
    return (short)(r >> 16);
}
static __device__ inline float bf2f(short b) {  // bf16 bits -> f32
    union { unsigned u; float f; } c{(unsigned)(unsigned short)b << 16};
    return c.f;
}

__global__ void vq_prep(const float* __restrict__ E,
                        float* __restrict__ ET,
                        float* __restrict__ ckseq,
                        char* __restrict__ EB) {
    #pragma clang fp contract(off)
    int n = blockIdx.x * blockDim.x + threadIdx.x;  // codebook col 0..1023
    if (n >= KCB) return;
    float col[DIM];
    float c = 0.f;
    #pragma unroll
    for (int d = 0; d < DIM; ++d) {
        float v = E[d * KCB + n];      // coalesced along n
        col[d] = v;
        ET[n * DIM + d] = v;
        float q = v * v;
        c = c + q;                     // sequential (numpy axis-0 reduce)
    }
    ckseq[n] = c;
    // EB layout: tile t = n>>4 (16 cols), col-in-tile l15 = n&15.
    // Part p: 0=hi d0-31, 1=hi d32-63, 2=lo d0-31, 3=lo d32-63.
    // Lane l = g*16+l15 holds d = (p&1)*32 + g*8 + j, j=0..7, 16 B per lane
    // at EB + t*4096 + p*1024 + l*16.  (-2e is an exact scale.)
    int t = n >> 4, l15 = n & 15;
    char* base = EB + t * 4096;
    #pragma unroll
    for (int p = 0; p < 4; ++p) {
        int dblk = p & 1, islo = p >> 1;
        #pragma unroll
        for (int g = 0; g < 4; ++g) {
            s16x8 w;
            #pragma unroll
            for (int j = 0; j < 8; ++j) {
                float m = -2.f * col[dblk * 32 + g * 8 + j];
                short h = bfb(m);
                w[j] = islo ? bfb(m - bf2f(h)) : h;
            }
            *(s16x8*)(base + p * 1024 + (g * 16 + l15) * 16) = w;
        }
    }
}

// One 16-col tile: 6 MFMA C-chained per row-tile + branchless top-2.
#define COMPUTE_TILE(T, BH0, BH1, BL0, BL1, CCK)                                   \
    {                                                                              \
        f32x4 cin = {(CCK), (CCK), (CCK), (CCK)};                                  \
        int kc = (T) * 16 + l15;                                                   \
        _Pragma("unroll")                                                          \
        for (int rt = 0; rt < 2; ++rt) {                                           \
            f32x4 acc = cin;   /* C-in = ||e||^2 */                                \
            acc = __builtin_amdgcn_mfma_f32_16x16x32_bf16(aH[rt][0], BH0, acc, 0, 0, 0); \
            acc = __builtin_amdgcn_mfma_f32_16x16x32_bf16(aH[rt][1], BH1, acc, 0, 0, 0); \
            acc = __builtin_amdgcn_mfma_f32_16x16x32_bf16(aL[rt][0], BH0, acc, 0, 0, 0); \
            acc = __builtin_amdgcn_mfma_f32_16x16x32_bf16(aL[rt][1], BH1, acc, 0, 0, 0); \
            acc = __builtin_amdgcn_mfma_f32_16x16x32_bf16(aH[rt][0], BL0, acc, 0, 0, 0); \
            acc = __builtin_amdgcn_mfma_f32_16x16x32_bf16(aH[rt][1], BL1, acc, 0, 0, 0); \
            _Pragma("unroll")                                                      \
            for (int rr = 0; rr < 4; ++rr) {                                       \
                float s = acc[rr];            /* = ck - 2*dot (hi/lo accurate) */  \
                int sl = rt * 4 + rr;                                              \
                bool cond = s < tb1[sl];                                           \
                tb2[sl] = __builtin_amdgcn_fmed3f(s, tb1[sl], tb2[sl]);            \
                tb1[sl] = fminf(tb1[sl], s);                                       \
                tix[sl] = cond ? kc : tix[sl];                                     \
            }                                                                      \
        }                                                                          \
    }

__global__ __launch_bounds__(256, 4)
__attribute__((amdgpu_waves_per_eu(4, 4)))
void vq_mfma(const float* __restrict__ x, const float* __restrict__ ck,
             const char* __restrict__ EB, const float* __restrict__ ET,
             float* __restrict__ out, int* __restrict__ count,
             int* __restrict__ list, int list_cap) {
    __shared__ float ckls[KCB + 16];     // +16: harmless pad-read at t=62
    __shared__ int idxbuf[128];

    const int tid  = threadIdx.x;
    const int lane = tid & 63;
    const int wv   = tid >> 6;            // wave 0..3
    const int l15  = lane & 15;
    const int g    = lane >> 4;           // 0..3
    const int rowbase = blockIdx.x * 128; // 128 rows per block, 32 per wave

    // ---- stage ck LUT once (only barrier in the kernel body) ----
    GLDS16(ck + wv * 256 + lane * 4, &ckls[wv * 256]);

    // ---- A fragments hi/lo: 2 rowtiles x 2 dblocks (32 VGPR persistent) ----
    s16x8 aH[2][2], aL[2][2];
    #pragma unroll
    for (int rt = 0; rt < 2; ++rt) {
        int row = rowbase + wv * 32 + rt * 16 + l15;
        const float* xp = x + (size_t)row * DIM + g * 8;
        #pragma unroll
        for (int s = 0; s < 2; ++s) {
            float val[8];
            float4 u = *(const float4*)(xp + s * 32);
            float4 v = *(const float4*)(xp + s * 32 + 4);
            val[0] = u.x; val[1] = u.y; val[2] = u.z; val[3] = u.w;
            val[4] = v.x; val[5] = v.y; val[6] = v.z; val[7] = v.w;
            s16x8 h, l;
            #pragma unroll
            for (int j = 0; j < 8; ++j) {
                short hb = bfb(val[j]);
                h[j] = hb;
                l[j] = bfb(val[j] - bf2f(hb));
            }
            aH[rt][s] = h;
            aL[rt][s] = l;
        }
    }
    __syncthreads();                      // ckls ready; no more block syncs

    // ---- top-2 state: slot = rt*4 + r -> row rt*16 + g*4 + r ----
    float tb1[8], tb2[8];
    int   tix[8];
    #pragma unroll
    for (int sl = 0; sl < 8; ++sl) { tb1[sl] = 1e30f; tb2[sl] = 1e30f; tix[sl] = 0; }

    // ---- barrier-free K-loop: per-wave B stream from L2, depth-1 prefetch --
    const char* ebp = EB + lane * 16;     // per-lane base
    s16x8 cH0 = *(const s16x8*)(ebp);
    s16x8 cH1 = *(const s16x8*)(ebp + 1024);
    s16x8 cL0 = *(const s16x8*)(ebp + 2048);
    s16x8 cL1 = *(const s16x8*)(ebp + 3072);
    float ckc = ckls[l15];

    #pragma unroll 1
    for (int t = 0; t < 64; t += 2) {
        // prefetch tile t+1 into n*
        const char* p1 = ebp + (size_t)(t + 1) * 4096;
        s16x8 nH0 = *(const s16x8*)(p1);
        s16x8 nH1 = *(const s16x8*)(p1 + 1024);
        s16x8 nL0 = *(const s16x8*)(p1 + 2048);
        s16x8 nL1 = *(const s16x8*)(p1 + 3072);
        float ckn = ckls[(t + 1) * 16 + l15];

        COMPUTE_TILE(t, cH0, cH1, cL0, cL1, ckc);

        // prefetch tile t+2 into c* (t=62 reads the pad tile; values unused)
        const char* p2 = ebp + (size_t)(t + 2) * 4096;
        cH0 = *(const s16x8*)(p2);
        cH1 = *(const s16x8*)(p2 + 1024);
        cL0 = *(const s16x8*)(p2 + 2048);
        cL1 = *(const s16x8*)(p2 + 3072);
        ckc = ckls[(t + 2) * 16 + l15];

        COMPUTE_TILE(t + 1, nH0, nH1, nL0, nL1, ckn);
    }

    // ---- merge top-2 across the 16 lanes of each g-group ----
    #pragma unroll
    for (int m = 1; m <= 8; m <<= 1) {
        #pragma unroll
        for (int sl = 0; sl < 8; ++sl) {
            float ob1 = __shfl_xor(tb1[sl], m);
            float ob2 = __shfl_xor(tb2[sl], m);
            int   oid = __shfl_xor(tix[sl], m);
            if (ob1 < tb1[sl] || (ob1 == tb1[sl] && oid < tix[sl])) {
                tb2[sl] = fminf(tb1[sl], ob2);
                tb1[sl] = ob1;
                tix[sl] = oid;
            } else {
                tb2[sl] = fminf(tb2[sl], ob1);
            }
        }
    }

    if (l15 == 0) {
        #pragma unroll
        for (int sl = 0; sl < 8; ++sl) {
            int rloc = wv * 32 + (sl >> 2) * 16 + g * 4 + (sl & 3);
            idxbuf[rloc] = tix[sl];
            if (tb2[sl] - tb1[sl] < MARGIN) {
                int slot = atomicAdd(count, 1);
                if (slot < list_cap) list[slot] = rowbase + rloc;
            }
        }
    }
    __syncthreads();

    // ---- fused gather: out[rowbase + r][:] = ET[idx[r]][:] ----
    const float4* ET4 = (const float4*)ET;
    float4* out4 = (float4*)(out + (size_t)rowbase * DIM);
    #pragma unroll
    for (int p = 0; p < 8; ++p) {
        int f = p * 256 + tid;           // 0..2047
        int r = f >> 4, dq = f & 15;
        out4[f] = ET4[idxbuf[r] * 16 + dq];
    }
}

// Exact numpy-f32-chain argmin for flagged rows (semantics validated R2-R9).
// One wave per row; lane handles 16 k's (k = c*64 + lane, coalesced E[d][k]
// loads, 2 chains interleaved). Packed-key (ordbits(dist)<<32)|k lex-min
// gives exact first-index tie-break. Gathers + rewrites the row directly.
__global__ __launch_bounds__(256)
void vq_refine2(const float* __restrict__ x, const float* __restrict__ E,
                const float* __restrict__ ckseq, const float* __restrict__ ET,
                float* __restrict__ out,
                const int* __restrict__ count, const int* __restrict__ list,
                int list_cap) {
    #pragma clang fp contract(off)
    int n = *count;
    if (n > list_cap) n = list_cap;
    int gw = (blockIdx.x * blockDim.x + threadIdx.x) >> 6;
    int lane = threadIdx.x & 63;
    int nw = (gridDim.x * blockDim.x) >> 6;
    for (int slot = gw; slot < n; slot += nw) {
        int row = list[slot];
        const f32x4* z4 = (const f32x4*)(x + (size_t)row * DIM);

        // ||z||^2: numpy pairwise_sum n=64 (8-acc unrolled), validated order
        float r8[8];
        {
            f32x4 a = z4[0], b = z4[1];
            r8[0] = a.x * a.x; r8[1] = a.y * a.y; r8[2] = a.z * a.z; r8[3] = a.w * a.w;
            r8[4] = b.x * b.x; r8[5] = b.y * b.y; r8[6] = b.z * b.z; r8[7] = b.w * b.w;
        }
        #pragma unroll
        for (int gi = 1; gi < 8; ++gi) {
            f32x4 a = z4[gi * 2], b = z4[gi * 2 + 1];
            r8[0] = r8[0] + a.x * a.x; r8[1] = r8[1] + a.y * a.y;
            r8[2] = r8[2] + a.z * a.z; r8[3] = r8[3] + a.w * a.w;
            r8[4] = r8[4] + b.x * b.x; r8[5] = r8[5] + b.y * b.y;
            r8[6] = r8[6] + b.z * b.z; r8[7] = r8[7] + b.w * b.w;
        }
        float A = ((r8[0] + r8[1]) + (r8[2] + r8[3]))
                + ((r8[4] + r8[5]) + (r8[6] + r8[7]));

        unsigned long long key = ~0ull;
        for (int c = 0; c < 16; c += 2) {     // 2 chains interleaved
            int k0 = c * 64 + lane, k1 = k0 + 64;
            float s0 = 0.f, s1 = 0.f;
            #pragma unroll
            for (int q = 0; q < 16; ++q) {    // sequential fmaf over d (BLAS emu)
                f32x4 zv = z4[q];
                s0 = fmaf(zv.x, E[(4 * q + 0) * KCB + k0], s0);
                s1 = fmaf(zv.x, E[(4 * q + 0) * KCB + k1], s1);
                s0 = fmaf(zv.y, E[(4 * q + 1) * KCB + k0], s0);
                s1 = fmaf(zv.y, E[(4 * q + 1) * KCB + k1], s1);
                s0 = fmaf(zv.z, E[(4 * q + 2) * KCB + k0], s0);
                s1 = fmaf(zv.z, E[(4 * q + 2) * KCB + k1], s1);
                s0 = fmaf(zv.w, E[(4 * q + 3) * KCB + k0], s0);
                s1 = fmaf(zv.w, E[(4 * q + 3) * KCB + k1], s1);
            }
            float d0 = (A + ckseq[k0]) - 2.0f * s0;
            float d1 = (A + ckseq[k1]) - 2.0f * s1;
            unsigned u0 = __float_as_uint(d0);
            unsigned o0 = u0 ^ ((u0 & 0x80000000u) ? 0xFFFFFFFFu : 0x80000000u);
            unsigned u1 = __float_as_uint(d1);
            unsigned o1 = u1 ^ ((u1 & 0x80000000u) ? 0xFFFFFFFFu : 0x80000000u);
            unsigned long long key0 = ((unsigned long long)o0 << 32) | (unsigned)k0;
            unsigned long long key1 = ((unsigned long long)o1 << 32) | (unsigned)k1;
            key = key0 < key ? key0 : key;
            key = key1 < key ? key1 : key;
        }
        #pragma unroll
        for (int off = 32; off; off >>= 1) {
            unsigned long long ok = __shfl_xor(key, off);
            key = ok < key ? ok : key;
        }
        unsigned bk = (unsigned)(key & 0xFFFFFFFFu);
        out[(size_t)row * DIM + lane] = ET[(size_t)bk * DIM + lane];
    }
}

extern "C" void kernel_launch(void* const* d_in, const int* in_sizes, int n_in,
                              void* d_out, int out_size, void* d_ws, size_t ws_size,
                              hipStream_t stream) {
    const float* x = (const float*)d_in[0];
    const float* E = (const float*)d_in[1];
    float* out = (float*)d_out;

    char* ws = (char*)d_ws;
    float* ET  = (float*)(ws + ET_OFF);
    float* ck  = (float*)(ws + CK_OFF);
    char*  EB  = ws + EB_OFF;
    int*   cnt = (int*)(ws + CNT_OFF);
    int*   lst = (int*)(ws + LIST_OFF);
    long long avail = (long long)ws_size - LIST_OFF;
    int list_cap = avail > 0 ? (int)(avail / 4) : 0;
    if (list_cap > LIST_CAP) list_cap = LIST_CAP;

    hipMemsetAsync(cnt, 0, sizeof(int), stream);
    vq_prep<<<4, 256, 0, stream>>>(E, ET, ck, EB);
    vq_mfma<<<NROWS / 128, 256, 0, stream>>>(x, ck, EB, ET, out, cnt, lst, list_cap);
    vq_refine2<<<512, 256, 0, stream>>>(x, E, ck, ET, out, cnt, lst, list_cap);
}